// Round 9
// baseline (402.812 us; speedup 1.0000x reference)
//
#include <hip/hip_runtime.h>
#include <math.h>

#define NPIX (2048*2048)
#define NBLOCKS 1024           // 4 blocks/CU, all resident in one round
#define CHUNK (NPIX/NBLOCKS)   // 4096 px per block
#define SPX 256
#define NGRP 8                 // 8 groups x 4 iters = 32 i-iters per wave

// global ws: NREP replicas of the 2305-float accumulator table (proven layout)
#define WS_T1 1024
#define WS_T2 2048
#define WS_F2 2304
#define WS_FLOATS 2305
#define NREP 32
#define RSTRIDE 2432
#define L_T1 1088
#define L_T2 2176
#define LDS_RED (2176 + 16*17)   // 2448 floats = 9792 B

typedef __attribute__((ext_vector_type(8))) short short8;
typedef __attribute__((ext_vector_type(4))) float f32x4;
typedef __attribute__((ext_vector_type(4))) unsigned int u32x4;

__device__ __forceinline__ unsigned int pk_trunc_bf16(float lo, float hi) {
    return __builtin_amdgcn_perm(__float_as_uint(hi), __float_as_uint(lo), 0x07060302u);
}
__device__ __forceinline__ unsigned int pk_lab(int lo, int hi) {
    return __builtin_amdgcn_perm((unsigned)hi, (unsigned)lo, 0x05040100u);
}
__device__ __forceinline__ unsigned int onehot2(unsigned int x, unsigned int tp) {
    const unsigned int a = x ^ tp;
    const unsigned int t = 0x40004000u - a;
    return t & 0x40004000u;
}

// asm-pinned 16B load (cannot be sunk/reordered) + counted wait & sched fence
__device__ __forceinline__ void gld4(u32x4& d, const void* a) {
    asm volatile("global_load_dwordx4 %0, %1, off" : "=v"(d) : "v"(a));
}
#define ASM_WAITVM(n) do { asm volatile("s_waitcnt vmcnt(" #n ")"); \
                           __builtin_amdgcn_sched_barrier(0); } while (0)

// ---------- clock probe: 30000 dependent FMAs ~ 120k cycles on one wave.
// dur_us ~= 120e3 / SCLK_MHz  (50 us @ 2.4 GHz, 200 us @ 600 MHz)
__global__ __launch_bounds__(64) void probe_clock(float* __restrict__ ws)
{
    float x = (float)threadIdx.x * 1.0000001f;
    #pragma unroll 1
    for (int i = 0; i < 7500; ++i) {
        x = fmaf(x, 1.0000001f, 1.0f);
        x = fmaf(x, 1.0000001f, 1.0f);
        x = fmaf(x, 1.0000001f, 1.0f);
        x = fmaf(x, 1.0000001f, 1.0f);
    }
    if (x == 12345.678f) ws[0] = x;   // never true; keeps the chain live
}

__global__ __launch_bounds__(256, 4) void agg_mfma(
    const float* __restrict__ pred,
    const int*   __restrict__ kl,
    const int*   __restrict__ rl,
    float* __restrict__ ws)
{
    __shared__ union {
        float lab[2][1024];   // [buf][wv*256 + lane*4] : 2 x 1 KB per wave
        float red[LDS_RED];
    } sh;
    __shared__ float s_f2w[4];

    const int tid  = threadIdx.x;
    const int wv   = tid >> 6;
    const int lane = tid & 63;
    const int quad = lane >> 4;
    const int col  = lane & 15;
    const int c8   = col & 7;
    const bool lowcol = (col < 8);
    const unsigned int cpack = (unsigned)col * 0x00010001u;
    const unsigned int tps[4] = {cpack, cpack + 0x00100010u,
                                 cpack + 0x00200020u, cpack + 0x00300030u};
    const unsigned int hc = (col == 8) ? 0x3F803F80u : 0u;
    const short8 b2c = __builtin_bit_cast(short8, (u32x4){hc, hc, hc, hc});

    f32x4 acc0[4], acc1[4], acc2;
    #pragma unroll
    for (int s = 0; s < 4; ++s) {
        acc0[s] = (f32x4){0.f, 0.f, 0.f, 0.f};
        acc1[s] = (f32x4){0.f, 0.f, 0.f, 0.f};
    }
    acc2 = (f32x4){0.f, 0.f, 0.f, 0.f};
    float f2 = 0.f;

    const int P0 = blockIdx.x * CHUNK;
    const int pbase = (2 * wv) * 32 + quad * 8;   // = 64*wv + quad*8
    const float* pp = pred + (size_t)c8 * NPIX + P0 + pbase;

    // Cooperative label pointer: one dwordx4 per GROUP fetches the wave's
    // full 4-iter label block (1 KB unique; replaces 16 duplicated loads).
    // lane -> {array, chunk-step, 16B slot}: addr dword idx == lane*4 in LDS.
    const int* labbase = (lane & 32) ? rl : kl;
    const int* lco = labbase + P0 + ((lane >> 4) & 1) * SPX + 64 * wv
                   + (lane & 15) * 4;

    u32x4 R;
    gld4(R, lco);                       // labels group 0
    ASM_WAITVM(0);
    *(u32x4*)&sh.lab[0][wv * 256 + lane * 4] = R;
    gld4(R, lco + 2 * SPX);             // labels group 1 (in flight during g0)

    #pragma unroll 1
    for (int g = 0; g < NGRP; ++g) {
        if (g < NGRP - 1) {
            ASM_WAITVM(0);              // R = labels(g+1) landed
            *(u32x4*)&sh.lab[(g + 1) & 1][wv * 256 + lane * 4] = R;
            if (g < NGRP - 2) gld4(R, lco + 2 * (g + 2) * SPX);
        }
        const float* lb0 = sh.lab[g & 1] + wv * 256 + quad * 8;
        #pragma unroll
        for (int j = 0; j < 4; ++j) {   // (cs,i) order == R3's (s,i) order
            const int i = j & 1, cs = j >> 1;
            const float* lb = lb0 + cs * 64 + i * 32;
            const int4 ka = *(const int4*)(lb);
            const int4 kb = *(const int4*)(lb + 4);
            const int4 ra = *(const int4*)(lb + 128);
            const int4 rb = *(const int4*)(lb + 132);
            const int off = (2 * g + cs) * SPX + i * 32;
            const float4 pa  = *(const float4*)(pp + off);
            const float4 pb4 = *(const float4*)(pp + off + 4);

            const int   klv[8] = {ka.x, ka.y, ka.z, ka.w, kb.x, kb.y, kb.z, kb.w};
            const int   rlv[8] = {ra.x, ra.y, ra.z, ra.w, rb.x, rb.y, rb.z, rb.w};
            const float pv[8]  = {pa.x, pa.y, pa.z, pa.w, pb4.x, pb4.y, pb4.z, pb4.w};

            float pr[8];
            #pragma unroll
            for (int jj = 0; jj < 8; ++jj) {
                pr[jj] = (rlv[jj] > 0) ? pv[jj] : 0.f;
                f2 = fmaf(pr[jj], pr[jj], f2);   // exact f32 sum of pr^2
            }
            unsigned int b1p[4], kp4[4], rp4[4];
            #pragma unroll
            for (int q = 0; q < 4; ++q) {
                const int j0 = 2 * q, j1 = 2 * q + 1;
                const unsigned int plo = pk_trunc_bf16(pv[j0], pv[j1]);
                const unsigned int phi = pk_trunc_bf16(pr[j0], pr[j1]);
                b1p[q] = lowcol ? plo : phi;
                kp4[q] = pk_lab(klv[j0], klv[j1]);
                rp4[q] = pk_lab(rlv[j0], rlv[j1]);
            }
            const short8 b1 = __builtin_bit_cast(short8,
                (u32x4){b1p[0], b1p[1], b1p[2], b1p[3]});

            #pragma unroll
            for (int t = 0; t < 4; ++t) {        // T0 + T1 share ohk
                u32x4 oh;
                #pragma unroll
                for (int q = 0; q < 4; ++q) oh[q] = onehot2(kp4[q], tps[t]);
                const short8 ak = __builtin_bit_cast(short8, oh);
                acc0[t] = __builtin_amdgcn_mfma_f32_16x16x32_bf16(ak, b1,  acc0[t], 0, 0, 0);
                acc1[t] = __builtin_amdgcn_mfma_f32_16x16x32_bf16(ak, b2c, acc1[t], 0, 0, 0);
            }
            u32x4 alo, bhi;                      // T2 radix: 1 MFMA
            #pragma unroll
            for (int q = 0; q < 4; ++q) {
                alo[q] = onehot2(rp4[q] & 0x000F000Fu, cpack);
                bhi[q] = onehot2((rp4[q] >> 4) & 0x00030003u, cpack);
            }
            acc2 = __builtin_amdgcn_mfma_f32_16x16x32_bf16(
                __builtin_bit_cast(short8, alo), __builtin_bit_cast(short8, bhi),
                acc2, 0, 0, 0);
        }
    }

    // --- f2: wave shuffle reduce
    #pragma unroll
    for (int off = 32; off > 0; off >>= 1) f2 += __shfl_down(f2, off, 64);
    if (lane == 0) s_f2w[wv] = f2;

    // --- cross-wave reduce, phased RMW (red unions over lab; barrier first)
    __syncthreads();
    for (int w = 0; w < 4; ++w) {
        if (wv == w) {
            #pragma unroll
            for (int t = 0; t < 4; ++t)
                #pragma unroll
                for (int i = 0; i < 4; ++i) {
                    const int l = t * 16 + quad * 4 + i;
                    const int a0 = l * 17 + col;
                    const int a1 = L_T1 + l * 17 + col;
                    if (w == 0) { sh.red[a0] = acc0[t][i]; sh.red[a1] = acc1[t][i]; }
                    else        { sh.red[a0] += acc0[t][i]; sh.red[a1] += acc1[t][i]; }
                }
            #pragma unroll
            for (int i = 0; i < 4; ++i) {
                const int a2 = L_T2 + (quad * 4 + i) * 17 + col;
                if (w == 0) sh.red[a2] = acc2[i]; else sh.red[a2] += acc2[i];
            }
        }
        __syncthreads();
    }
    float* wsr = ws + (size_t)(blockIdx.x & (NREP - 1)) * RSTRIDE;
    if (tid == 0)
        atomicAdd(&wsr[WS_F2], s_f2w[0] + s_f2w[1] + s_f2w[2] + s_f2w[3]);
    for (int idx = tid; idx < 2304; idx += 256) {
        int a;
        if (idx < 1024)      a = (idx >> 4) * 17 + (idx & 15);
        else if (idx < 2048) a = L_T1 + ((idx - 1024) >> 4) * 17 + (idx & 15);
        else                 a = L_T2 + ((idx - 2048) >> 4) * 17 + (idx & 15);
        atomicAdd(&wsr[idx], sh.red[a]);
    }
}

// fold NREP replicas into replica 0 (L2-hot)
__global__ __launch_bounds__(256) void agg_reduce(float* __restrict__ ws)
{
    const int i = blockIdx.x * 256 + threadIdx.x;
    if (i >= WS_FLOATS) return;
    float s = ws[i];
    #pragma unroll 4
    for (int r = 1; r < NREP; ++r) s += ws[i + (size_t)r * RSTRIDE];
    ws[i] = s;
}

__global__ __launch_bounds__(64) void agg_final(const float* __restrict__ ws,
                                                float* __restrict__ out)
{
    const int l = threadIdx.x;
    const float* t0 = ws + l * 16;
    const float pck = 0.5f  * ws[WS_T1 + l * 16 + 8];
    const float pcr = 0.25f * ws[WS_T2 + (l & 15) * 16 + (l >> 4)];

    float corr = 0.f;
    if (l > 0) {
        #pragma unroll
        for (int c = 0; c < 8; ++c) {
            const float seg = 0.5f * t0[c];
            const float T   = 0.5f * t0[8 + c];
            const float gk  = seg / (pck + 1.f);
            corr += gk * (gk * pck - 2.f * T);
        }
    }
    const float rcard = (l > 0) ? pcr : 0.f;
    float S = pcr / (rcard + 1.f);
    int mx = (pcr > 0.5f) ? l : 0;
    float f2 = (l == 0) ? 0.5f * ws[WS_F2] : 0.f;

    #pragma unroll
    for (int off = 32; off > 0; off >>= 1) {
        f2   += __shfl_down(f2, off, 64);
        corr += __shfl_down(corr, off, 64);
        S    += __shfl_down(S, off, 64);
        mx    = max(mx, __shfl_down(mx, off, 64));
    }
    if (l == 0) {
        const float SS = f2 + corr;
        float D = sqrtf(fmaxf(SS, 0.f)) - 0.5f;
        D = fmaxf(D, 0.f);
        out[0] = logf(D * D + 1.f) * S / (float)max(mx, 1);
    }
}

extern "C" void kernel_launch(void* const* d_in, const int* in_sizes, int n_in,
                              void* d_out, int out_size, void* d_ws, size_t ws_size,
                              hipStream_t stream) {
    const float* pred = (const float*)d_in[0];
    const int* kl = (const int*)d_in[3];
    const int* rl = (const int*)d_in[4];
    float* ws = (float*)d_ws;

    // clock probe (scratch write never happens; runs before memset anyway)
    probe_clock<<<1, 64, 0, stream>>>(ws);

    hipMemsetAsync(d_ws, 0, (size_t)NREP * RSTRIDE * sizeof(float), stream);
    agg_mfma<<<NBLOCKS, 256, 0, stream>>>(pred, kl, rl, ws);
    agg_reduce<<<(WS_FLOATS + 255) / 256, 256, 0, stream>>>(ws);
    agg_final<<<1, 64, 0, stream>>>(ws, (float*)d_out);
}

// Round 10
// 267.633 us; speedup vs baseline: 1.5051x; 1.5051x over previous
//
#include <hip/hip_runtime.h>
#include <math.h>

#define NPIX (2048*2048)
#define NBLOCKS 1024           // 4 blocks/CU, all resident in one round
#define CHUNK (NPIX/NBLOCKS)   // 4096 px per block
#define SPX 256
#define NGRP 8                 // 8 groups x 4 iters = 32 i-iters per wave

// global ws: NREP replicas of the 2305-float accumulator table (proven layout)
#define WS_T1 1024
#define WS_T2 2048
#define WS_F2 2304
#define WS_FLOATS 2305
#define NREP 32
#define RSTRIDE 2432
#define L_T1 1088
#define L_T2 2176
#define LDS_RED (2176 + 16*17)   // 2448 floats

// per-wave LDS: pred double-buf 2x1024 fl + labels 256 fl = 2304 fl (9216 B)
#define WSTRIDE 2304
#define LAB_OFF 2048
#define STAGE_FLOATS (4*WSTRIDE) // 9216 fl = 36864 B per block (4/CU = 147 KB)

typedef __attribute__((ext_vector_type(8))) short short8;
typedef __attribute__((ext_vector_type(4))) float f32x4;
typedef __attribute__((ext_vector_type(4))) unsigned int u32x4;

typedef __attribute__((address_space(3))) unsigned int lds_uint;
typedef __attribute__((address_space(1))) unsigned int glb_uint;

__device__ __forceinline__ unsigned int pk_trunc_bf16(float lo, float hi) {
    return __builtin_amdgcn_perm(__float_as_uint(hi), __float_as_uint(lo), 0x07060302u);
}
__device__ __forceinline__ unsigned int pk_lab(int lo, int hi) {
    return __builtin_amdgcn_perm((unsigned)hi, (unsigned)lo, 0x05040100u);
}
__device__ __forceinline__ unsigned int onehot2(unsigned int x, unsigned int tp) {
    const unsigned int a = x ^ tp;
    const unsigned int t = 0x40004000u - a;
    return t & 0x40004000u;
}

// asm-pinned 16B load to regs (cannot be sunk) — proven in R8/R9
__device__ __forceinline__ void gld4(u32x4& d, const void* a) {
    asm volatile("global_load_dwordx4 %0, %1, off" : "=v"(d) : "v"(a));
}
// counted wait: memory clobber (orders LDS reads at IR level) + sched fence
#define ASM_WAITVM(n) do { asm volatile("s_waitcnt vmcnt(" #n ")" ::: "memory"); \
                           __builtin_amdgcn_sched_barrier(0); } while (0)

__global__ __launch_bounds__(256, 4) void agg_mfma(
    const float* __restrict__ pred,
    const int*   __restrict__ kl,
    const int*   __restrict__ rl,
    float* __restrict__ ws)
{
    __shared__ union {
        float stage[STAGE_FLOATS];   // 36864 B, per-wave-private slices
        float red[LDS_RED];
    } sh;
    __shared__ float s_f2w[4];

    const int tid  = threadIdx.x;
    const int wv   = tid >> 6;
    const int lane = tid & 63;
    const int quad = lane >> 4;
    const int col  = lane & 15;
    const int c8   = col & 7;
    const bool lowcol = (col < 8);
    const unsigned int cpack = (unsigned)col * 0x00010001u;
    const unsigned int tps[4] = {cpack, cpack + 0x00100010u,
                                 cpack + 0x00200020u, cpack + 0x00300030u};
    const unsigned int hc = (col == 8) ? 0x3F803F80u : 0u;
    const short8 b2c = __builtin_bit_cast(short8, (u32x4){hc, hc, hc, hc});

    f32x4 acc0[4], acc1[4], acc2;
    #pragma unroll
    for (int s = 0; s < 4; ++s) {
        acc0[s] = (f32x4){0.f, 0.f, 0.f, 0.f};
        acc1[s] = (f32x4){0.f, 0.f, 0.f, 0.f};
    }
    acc2 = (f32x4){0.f, 0.f, 0.f, 0.f};
    float f2 = 0.f;

    const int P0 = blockIdx.x * CHUNK;
    const int wbase = wv * WSTRIDE;

    // ---- label pipeline (R9 proven scheme): 1 gld/group -> reg -> LDS
    const int* labarr = (lane & 32) ? rl : kl;
    const int* lg = labarr + P0 + ((lane >> 4) & 1) * SPX + 64 * wv
                  + (lane & 15) * 4;
    const int lwl = wbase + LAB_OFF + lane * 4;

    // ---- pred DMA source pointers (per instr m): chunk c=4m+(lane>>4),
    // ch=c>>1, cs=c&1, 16B/lane; source pre-swizzled so linear LDS dest
    // yields lds[c*64 + x] = global[x ^ swz(c)]  (m104/m173 pattern)
    const int s16 = lane & 15;
    const float* psrc[4];
    #pragma unroll
    for (int m = 0; m < 4; ++m) {
        const int c = 4 * m + (lane >> 4);
        const int swz = ((c & 3) << 3) | (((c >> 2) & 1) << 2);
        psrc[m] = pred + (size_t)(c >> 1) * NPIX + P0 + (c & 1) * SPX
                + 64 * wv + ((4 * s16) ^ swz);
    }
    // pred read base offsets per cs (lane-constant), swizzled
    int pr0[2];
    #pragma unroll
    for (int cs = 0; cs < 2; ++cs) {
        const int ck = 2 * c8 + cs;
        const int swz = ((ck & 3) << 3) | (((ck >> 2) & 1) << 2);
        pr0[cs] = ck * 64 + ((quad * 8) ^ swz);
    }

    // one group's pred: 4 global_load_lds (wave-uniform LDS base + lane*16)
    auto DMA4 = [&](int b, int g) {
        #pragma unroll
        for (int m = 0; m < 4; ++m)
            __builtin_amdgcn_global_load_lds(
                (const glb_uint*)(psrc[m] + 2 * g * SPX),
                (lds_uint*)&sh.stage[wbase + b * 1024 + m * 256], 16, 0, 0);
    };

    // ---- prologue: establish steady state (9 VMEM outstanding)
    u32x4 Rl;
    gld4(Rl, lg);                 // lab(0)            [1]
    DMA4(0, 0);                   // pred(0) -> buf0   [5]
    ASM_WAITVM(4);                // lab(0) landed
    *(u32x4*)&sh.stage[lwl] = Rl;
    gld4(Rl, lg + 2 * SPX);       // lab(1)            [5]
    DMA4(1, 1);                   // pred(1) -> buf1   [9]

    #pragma unroll 1
    for (int g = 0; g < NGRP; ++g) {
        // pred(g) retired -> visible in LDS; later groups stay in flight
        if (g < NGRP - 1) { ASM_WAITVM(5); } else { ASM_WAITVM(0); }
        const int pbuf = wbase + (g & 1) * 1024;

        #pragma unroll
        for (int j = 0; j < 4; ++j) {          // (cs,i) order == R3/R9
            const int i = j & 1, cs = j >> 1;
            const int lb = wbase + LAB_OFF + cs * 64 + i * 32 + quad * 8;
            const int4 ka = *(const int4*)&sh.stage[lb];
            const int4 kb = *(const int4*)&sh.stage[lb + 4];
            const int4 ra = *(const int4*)&sh.stage[lb + 128];
            const int4 rb = *(const int4*)&sh.stage[lb + 132];
            const int poff = pbuf + pr0[cs] + i * 32;
            const float4 pa  = *(const float4*)&sh.stage[poff];
            const float4 pb4 = *(const float4*)&sh.stage[poff + 4];

            const int   klv[8] = {ka.x, ka.y, ka.z, ka.w, kb.x, kb.y, kb.z, kb.w};
            const int   rlv[8] = {ra.x, ra.y, ra.z, ra.w, rb.x, rb.y, rb.z, rb.w};
            const float pv[8]  = {pa.x, pa.y, pa.z, pa.w, pb4.x, pb4.y, pb4.z, pb4.w};

            float pr[8];
            #pragma unroll
            for (int jj = 0; jj < 8; ++jj) {
                pr[jj] = (rlv[jj] > 0) ? pv[jj] : 0.f;
                f2 = fmaf(pr[jj], pr[jj], f2);   // exact f32 sum of pr^2
            }
            unsigned int b1p[4], kp4[4], rp4[4];
            #pragma unroll
            for (int q = 0; q < 4; ++q) {
                const int j0 = 2 * q, j1 = 2 * q + 1;
                const unsigned int plo = pk_trunc_bf16(pv[j0], pv[j1]);
                const unsigned int phi = pk_trunc_bf16(pr[j0], pr[j1]);
                b1p[q] = lowcol ? plo : phi;
                kp4[q] = pk_lab(klv[j0], klv[j1]);
                rp4[q] = pk_lab(rlv[j0], rlv[j1]);
            }
            const short8 b1 = __builtin_bit_cast(short8,
                (u32x4){b1p[0], b1p[1], b1p[2], b1p[3]});

            #pragma unroll
            for (int t = 0; t < 4; ++t) {        // T0 + T1 share ohk
                u32x4 oh;
                #pragma unroll
                for (int q = 0; q < 4; ++q) oh[q] = onehot2(kp4[q], tps[t]);
                const short8 ak = __builtin_bit_cast(short8, oh);
                acc0[t] = __builtin_amdgcn_mfma_f32_16x16x32_bf16(ak, b1,  acc0[t], 0, 0, 0);
                acc1[t] = __builtin_amdgcn_mfma_f32_16x16x32_bf16(ak, b2c, acc1[t], 0, 0, 0);
            }
            u32x4 alo, bhi;                      // T2 radix: 1 MFMA
            #pragma unroll
            for (int q = 0; q < 4; ++q) {
                alo[q] = onehot2(rp4[q] & 0x000F000Fu, cpack);
                bhi[q] = onehot2((rp4[q] >> 4) & 0x00030003u, cpack);
            }
            acc2 = __builtin_amdgcn_mfma_f32_16x16x32_bf16(
                __builtin_bit_cast(short8, alo), __builtin_bit_cast(short8, bhi),
                acc2, 0, 0, 0);
        }

        if (g < NGRP - 1) {
            ASM_WAITVM(4);                 // lab(g+1) landed (oldest of 5)
            *(u32x4*)&sh.stage[lwl] = Rl;  // labels(g+1); g's reads are done
            if (g < NGRP - 2) {
                gld4(Rl, lg + (g + 2) * 2 * SPX);   // lab(g+2)
                DMA4(g & 1, g + 2);                 // pred(g+2) over buf(g&1)
            }                                       // -> 9 outstanding again
        }
    }

    // --- f2: wave shuffle reduce
    #pragma unroll
    for (int off = 32; off > 0; off >>= 1) f2 += __shfl_down(f2, off, 64);
    if (lane == 0) s_f2w[wv] = f2;

    // --- cross-wave reduce, phased RMW (red unions over stage)
    __syncthreads();
    for (int w = 0; w < 4; ++w) {
        if (wv == w) {
            #pragma unroll
            for (int t = 0; t < 4; ++t)
                #pragma unroll
                for (int i = 0; i < 4; ++i) {
                    const int l = t * 16 + quad * 4 + i;
                    const int a0 = l * 17 + col;
                    const int a1 = L_T1 + l * 17 + col;
                    if (w == 0) { sh.red[a0] = acc0[t][i]; sh.red[a1] = acc1[t][i]; }
                    else        { sh.red[a0] += acc0[t][i]; sh.red[a1] += acc1[t][i]; }
                }
            #pragma unroll
            for (int i = 0; i < 4; ++i) {
                const int a2 = L_T2 + (quad * 4 + i) * 17 + col;
                if (w == 0) sh.red[a2] = acc2[i]; else sh.red[a2] += acc2[i];
            }
        }
        __syncthreads();
    }
    float* wsr = ws + (size_t)(blockIdx.x & (NREP - 1)) * RSTRIDE;
    if (tid == 0)
        atomicAdd(&wsr[WS_F2], s_f2w[0] + s_f2w[1] + s_f2w[2] + s_f2w[3]);
    for (int idx = tid; idx < 2304; idx += 256) {
        int a;
        if (idx < 1024)      a = (idx >> 4) * 17 + (idx & 15);
        else if (idx < 2048) a = L_T1 + ((idx - 1024) >> 4) * 17 + (idx & 15);
        else                 a = L_T2 + ((idx - 2048) >> 4) * 17 + (idx & 15);
        atomicAdd(&wsr[idx], sh.red[a]);
    }
}

// fold NREP replicas into replica 0 (L2-hot)
__global__ __launch_bounds__(256) void agg_reduce(float* __restrict__ ws)
{
    const int i = blockIdx.x * 256 + threadIdx.x;
    if (i >= WS_FLOATS) return;
    float s = ws[i];
    #pragma unroll 4
    for (int r = 1; r < NREP; ++r) s += ws[i + (size_t)r * RSTRIDE];
    ws[i] = s;
}

__global__ __launch_bounds__(64) void agg_final(const float* __restrict__ ws,
                                                float* __restrict__ out)
{
    const int l = threadIdx.x;
    const float* t0 = ws + l * 16;
    const float pck = 0.5f  * ws[WS_T1 + l * 16 + 8];
    const float pcr = 0.25f * ws[WS_T2 + (l & 15) * 16 + (l >> 4)];

    float corr = 0.f;
    if (l > 0) {
        #pragma unroll
        for (int c = 0; c < 8; ++c) {
            const float seg = 0.5f * t0[c];
            const float T   = 0.5f * t0[8 + c];
            const float gk  = seg / (pck + 1.f);
            corr += gk * (gk * pck - 2.f * T);
        }
    }
    const float rcard = (l > 0) ? pcr : 0.f;
    float S = pcr / (rcard + 1.f);
    int mx = (pcr > 0.5f) ? l : 0;
    float f2 = (l == 0) ? 0.5f * ws[WS_F2] : 0.f;

    #pragma unroll
    for (int off = 32; off > 0; off >>= 1) {
        f2   += __shfl_down(f2, off, 64);
        corr += __shfl_down(corr, off, 64);
        S    += __shfl_down(S, off, 64);
        mx    = max(mx, __shfl_down(mx, off, 64));
    }
    if (l == 0) {
        const float SS = f2 + corr;
        float D = sqrtf(fmaxf(SS, 0.f)) - 0.5f;
        D = fmaxf(D, 0.f);
        out[0] = logf(D * D + 1.f) * S / (float)max(mx, 1);
    }
}

extern "C" void kernel_launch(void* const* d_in, const int* in_sizes, int n_in,
                              void* d_out, int out_size, void* d_ws, size_t ws_size,
                              hipStream_t stream) {
    const float* pred = (const float*)d_in[0];
    const int* kl = (const int*)d_in[3];
    const int* rl = (const int*)d_in[4];
    float* ws = (float*)d_ws;

    hipMemsetAsync(d_ws, 0, (size_t)NREP * RSTRIDE * sizeof(float), stream);
    agg_mfma<<<NBLOCKS, 256, 0, stream>>>(pred, kl, rl, ws);
    agg_reduce<<<(WS_FLOATS + 255) / 256, 256, 0, stream>>>(ws);
    agg_final<<<1, 64, 0, stream>>>(ws, (float*)d_out);
}

// Round 11
// 255.076 us; speedup vs baseline: 1.5792x; 1.0492x over previous
//
#include <hip/hip_runtime.h>
#include <math.h>

#define NPIX (2048*2048)
#define NBLOCKS 1024           // 4 blocks/CU, all resident in one round
#define CHUNK (NPIX/NBLOCKS)   // 4096 px per block
#define SPX 256
#define NGRP 8                 // 8 groups x 4 iters = 32 i-iters per wave

// global ws: NREP replicas of the 2305-float accumulator table (proven layout)
#define WS_T1 1024
#define WS_T2 2048
#define WS_F2 2304
#define WS_FLOATS 2305
#define NREP 32
#define RSTRIDE 2432
#define L_T1 1088
#define L_T2 2176
#define LDS_RED (2176 + 16*17)   // 2448 floats = 9792 B

typedef __attribute__((ext_vector_type(8))) short short8;
typedef __attribute__((ext_vector_type(4))) float f32x4;
typedef __attribute__((ext_vector_type(4))) unsigned int u32x4;

__device__ __forceinline__ unsigned int pk_trunc_bf16(float lo, float hi) {
    return __builtin_amdgcn_perm(__float_as_uint(hi), __float_as_uint(lo), 0x07060302u);
}
__device__ __forceinline__ unsigned int pk_lab(int lo, int hi) {
    return __builtin_amdgcn_perm((unsigned)hi, (unsigned)lo, 0x05040100u);
}
__device__ __forceinline__ unsigned int onehot2(unsigned int x, unsigned int tp) {
    const unsigned int a = x ^ tp;
    const unsigned int t = 0x40004000u - a;
    return t & 0x40004000u;
}

// asm-pinned 16B load (cannot be sunk/reordered) + counted wait & sched fence
__device__ __forceinline__ void gld4(u32x4& d, const void* a) {
    asm volatile("global_load_dwordx4 %0, %1, off" : "=v"(d) : "v"(a));
}
#define ASM_WAITVM(n) do { asm volatile("s_waitcnt vmcnt(" #n ")" ::: "memory"); \
                           __builtin_amdgcn_sched_barrier(0); } while (0)

__global__ __launch_bounds__(256, 4) void agg_mfma(
    const float* __restrict__ pred,
    const int*   __restrict__ kl,
    const int*   __restrict__ rl,
    float* __restrict__ ws)
{
    __shared__ union {
        float lab[2][1024];   // [buf][wv*256 + lane*4] : 2 x 1 KB per wave
        float red[LDS_RED];
    } sh;
    __shared__ float s_f2w[4];

    const int tid  = threadIdx.x;
    const int wv   = tid >> 6;
    const int lane = tid & 63;
    const int quad = lane >> 4;
    const int col  = lane & 15;
    const int c8   = col & 7;
    const bool lowcol = (col < 8);
    const unsigned int cpack = (unsigned)col * 0x00010001u;
    const unsigned int tps[4] = {cpack, cpack + 0x00100010u,
                                 cpack + 0x00200020u, cpack + 0x00300030u};
    const unsigned int hc = (col == 8) ? 0x3F803F80u : 0u;
    const short8 b2c = __builtin_bit_cast(short8, (u32x4){hc, hc, hc, hc});

    f32x4 acc0[4], acc1[4], acc2;
    #pragma unroll
    for (int s = 0; s < 4; ++s) {
        acc0[s] = (f32x4){0.f, 0.f, 0.f, 0.f};
        acc1[s] = (f32x4){0.f, 0.f, 0.f, 0.f};
    }
    acc2 = (f32x4){0.f, 0.f, 0.f, 0.f};
    float f2 = 0.f;

    const int P0 = blockIdx.x * CHUNK;
    const int pbase = (2 * wv) * 32 + quad * 8;   // = 64*wv + quad*8
    const float* pp = pred + (size_t)c8 * NPIX + P0 + pbase;

    // Cooperative label pipeline (proven R9): ONE dwordx4 per 4-iter group
    // fetches the wave's full label block (1 KB unique, perfectly coalesced;
    // replaces 16 duplicated per-quad loads). reg -> LDS double-buffer.
    const int* labbase = (lane & 32) ? rl : kl;
    const int* lco = labbase + P0 + ((lane >> 4) & 1) * SPX + 64 * wv
                   + (lane & 15) * 4;

    u32x4 R;
    gld4(R, lco);                       // labels group 0
    ASM_WAITVM(0);
    *(u32x4*)&sh.lab[0][wv * 256 + lane * 4] = R;
    gld4(R, lco + 2 * SPX);             // labels group 1 (in flight during g0)

    #pragma unroll 1
    for (int g = 0; g < NGRP; ++g) {
        if (g < NGRP - 1) {
            ASM_WAITVM(0);              // R = labels(g+1) landed
            *(u32x4*)&sh.lab[(g + 1) & 1][wv * 256 + lane * 4] = R;
            if (g < NGRP - 2) gld4(R, lco + 2 * (g + 2) * SPX);
        }
        const float* lb0 = sh.lab[g & 1] + wv * 256 + quad * 8;
        #pragma unroll
        for (int j = 0; j < 4; ++j) {   // (cs,i) order == R3's (s,i) order
            const int i = j & 1, cs = j >> 1;
            const float* lb = lb0 + cs * 64 + i * 32;
            const int4 ka = *(const int4*)(lb);
            const int4 kb = *(const int4*)(lb + 4);
            const int4 ra = *(const int4*)(lb + 128);
            const int4 rb = *(const int4*)(lb + 132);
            const int off = (2 * g + cs) * SPX + i * 32;
            const float4 pa  = *(const float4*)(pp + off);
            const float4 pb4 = *(const float4*)(pp + off + 4);

            const int   klv[8] = {ka.x, ka.y, ka.z, ka.w, kb.x, kb.y, kb.z, kb.w};
            const int   rlv[8] = {ra.x, ra.y, ra.z, ra.w, rb.x, rb.y, rb.z, rb.w};
            const float pv[8]  = {pa.x, pa.y, pa.z, pa.w, pb4.x, pb4.y, pb4.z, pb4.w};

            float pr[8];
            #pragma unroll
            for (int jj = 0; jj < 8; ++jj) {
                pr[jj] = (rlv[jj] > 0) ? pv[jj] : 0.f;
                f2 = fmaf(pr[jj], pr[jj], f2);   // exact f32 sum of pr^2
            }
            unsigned int b1p[4], kp4[4], rp4[4];
            #pragma unroll
            for (int q = 0; q < 4; ++q) {
                const int j0 = 2 * q, j1 = 2 * q + 1;
                const unsigned int plo = pk_trunc_bf16(pv[j0], pv[j1]);
                const unsigned int phi = pk_trunc_bf16(pr[j0], pr[j1]);
                b1p[q] = lowcol ? plo : phi;
                kp4[q] = pk_lab(klv[j0], klv[j1]);
                rp4[q] = pk_lab(rlv[j0], rlv[j1]);
            }
            const short8 b1 = __builtin_bit_cast(short8,
                (u32x4){b1p[0], b1p[1], b1p[2], b1p[3]});

            #pragma unroll
            for (int t = 0; t < 4; ++t) {        // T0 + T1 share ohk
                u32x4 oh;
                #pragma unroll
                for (int q = 0; q < 4; ++q) oh[q] = onehot2(kp4[q], tps[t]);
                const short8 ak = __builtin_bit_cast(short8, oh);
                acc0[t] = __builtin_amdgcn_mfma_f32_16x16x32_bf16(ak, b1,  acc0[t], 0, 0, 0);
                acc1[t] = __builtin_amdgcn_mfma_f32_16x16x32_bf16(ak, b2c, acc1[t], 0, 0, 0);
            }
            u32x4 alo, bhi;                      // T2 radix: 1 MFMA
            #pragma unroll
            for (int q = 0; q < 4; ++q) {
                alo[q] = onehot2(rp4[q] & 0x000F000Fu, cpack);
                bhi[q] = onehot2((rp4[q] >> 4) & 0x00030003u, cpack);
            }
            acc2 = __builtin_amdgcn_mfma_f32_16x16x32_bf16(
                __builtin_bit_cast(short8, alo), __builtin_bit_cast(short8, bhi),
                acc2, 0, 0, 0);
        }
    }

    // --- f2: wave shuffle reduce
    #pragma unroll
    for (int off = 32; off > 0; off >>= 1) f2 += __shfl_down(f2, off, 64);
    if (lane == 0) s_f2w[wv] = f2;

    // --- cross-wave reduce, phased RMW (red unions over lab; barrier first)
    __syncthreads();
    for (int w = 0; w < 4; ++w) {
        if (wv == w) {
            #pragma unroll
            for (int t = 0; t < 4; ++t)
                #pragma unroll
                for (int i = 0; i < 4; ++i) {
                    const int l = t * 16 + quad * 4 + i;
                    const int a0 = l * 17 + col;
                    const int a1 = L_T1 + l * 17 + col;
                    if (w == 0) { sh.red[a0] = acc0[t][i]; sh.red[a1] = acc1[t][i]; }
                    else        { sh.red[a0] += acc0[t][i]; sh.red[a1] += acc1[t][i]; }
                }
            #pragma unroll
            for (int i = 0; i < 4; ++i) {
                const int a2 = L_T2 + (quad * 4 + i) * 17 + col;
                if (w == 0) sh.red[a2] = acc2[i]; else sh.red[a2] += acc2[i];
            }
        }
        __syncthreads();
    }
    float* wsr = ws + (size_t)(blockIdx.x & (NREP - 1)) * RSTRIDE;
    if (tid == 0)
        atomicAdd(&wsr[WS_F2], s_f2w[0] + s_f2w[1] + s_f2w[2] + s_f2w[3]);
    for (int idx = tid; idx < 2304; idx += 256) {
        int a;
        if (idx < 1024)      a = (idx >> 4) * 17 + (idx & 15);
        else if (idx < 2048) a = L_T1 + ((idx - 1024) >> 4) * 17 + (idx & 15);
        else                 a = L_T2 + ((idx - 2048) >> 4) * 17 + (idx & 15);
        atomicAdd(&wsr[idx], sh.red[a]);
    }
}

// fold NREP replicas into replica 0 (L2-hot)
__global__ __launch_bounds__(256) void agg_reduce(float* __restrict__ ws)
{
    const int i = blockIdx.x * 256 + threadIdx.x;
    if (i >= WS_FLOATS) return;
    float s = ws[i];
    #pragma unroll 4
    for (int r = 1; r < NREP; ++r) s += ws[i + (size_t)r * RSTRIDE];
    ws[i] = s;
}

__global__ __launch_bounds__(64) void agg_final(const float* __restrict__ ws,
                                                float* __restrict__ out)
{
    const int l = threadIdx.x;
    const float* t0 = ws + l * 16;
    const float pck = 0.5f  * ws[WS_T1 + l * 16 + 8];
    const float pcr = 0.25f * ws[WS_T2 + (l & 15) * 16 + (l >> 4)];

    float corr = 0.f;
    if (l > 0) {
        #pragma unroll
        for (int c = 0; c < 8; ++c) {
            const float seg = 0.5f * t0[c];
            const float T   = 0.5f * t0[8 + c];
            const float gk  = seg / (pck + 1.f);
            corr += gk * (gk * pck - 2.f * T);
        }
    }
    const float rcard = (l > 0) ? pcr : 0.f;
    float S = pcr / (rcard + 1.f);
    int mx = (pcr > 0.5f) ? l : 0;
    float f2 = (l == 0) ? 0.5f * ws[WS_F2] : 0.f;

    #pragma unroll
    for (int off = 32; off > 0; off >>= 1) {
        f2   += __shfl_down(f2, off, 64);
        corr += __shfl_down(corr, off, 64);
        S    += __shfl_down(S, off, 64);
        mx    = max(mx, __shfl_down(mx, off, 64));
    }
    if (l == 0) {
        const float SS = f2 + corr;
        float D = sqrtf(fmaxf(SS, 0.f)) - 0.5f;
        D = fmaxf(D, 0.f);
        out[0] = logf(D * D + 1.f) * S / (float)max(mx, 1);
    }
}

extern "C" void kernel_launch(void* const* d_in, const int* in_sizes, int n_in,
                              void* d_out, int out_size, void* d_ws, size_t ws_size,
                              hipStream_t stream) {
    const float* pred = (const float*)d_in[0];
    const int* kl = (const int*)d_in[3];
    const int* rl = (const int*)d_in[4];
    float* ws = (float*)d_ws;

    hipMemsetAsync(d_ws, 0, (size_t)NREP * RSTRIDE * sizeof(float), stream);
    agg_mfma<<<NBLOCKS, 256, 0, stream>>>(pred, kl, rl, ws);
    agg_reduce<<<(WS_FLOATS + 255) / 256, 256, 0, stream>>>(ws);
    agg_final<<<1, 64, 0, stream>>>(ws, (float*)d_out);
}